// Round 1
// baseline (194.705 us; speedup 1.0000x reference)
//
#include <hip/hip_runtime.h>
#include <math.h>

#define HH 256
#define WW 256
#define NB 4
#define NN 256
#define NSTEPS 50
#define STEPSZ 0.1f
#define ALPHA 0.01f
#define BETA 0.005f
#define DMAX 15.0f

struct Flt { float g[13]; float dg[13]; };

// Pass 1: horizontal separable conv. One block = one image row (256 px).
// Produces per-pixel float4: (g*pd, dg*pd, g*|pd|, dg*|pd|)
__global__ void conv_h_kernel(const float* __restrict__ pd,
                              float4* __restrict__ interm, Flt flt) {
    int row = blockIdx.x;            // b*H + y
    int x = threadIdx.x;
    __shared__ float srow[WW + 12];
    const float* prow = pd + (size_t)row * WW;
    srow[6 + x] = prow[x];
    if (x < 6) { srow[x] = 0.f; srow[WW + 6 + x] = 0.f; }  // zero pad halo
    __syncthreads();
    float sg = 0.f, sdg = 0.f, sga = 0.f, sdga = 0.f;
#pragma unroll
    for (int j = 0; j < 13; ++j) {
        float v = srow[x + j];
        float a = fabsf(v);
        sg   += flt.g[j]  * v;
        sdg  += flt.dg[j] * v;
        sga  += flt.g[j]  * a;
        sdga += flt.dg[j] * a;
    }
    interm[(size_t)row * WW + x] = make_float4(sg, sdg, sga, sdga);
}

// Pass 2: vertical. Output per-pixel float4: (gimg0, gimg1, gimgW0, gimgW1)*10
__global__ void conv_v_kernel(const float4* __restrict__ interm,
                              float4* __restrict__ gimg4, Flt flt) {
    int row = blockIdx.x;            // b*H + y
    int b = row / HH;
    int y = row % HH;
    int x = threadIdx.x;
    float g0 = 0.f, g1 = 0.f, w0 = 0.f, w1 = 0.f;
#pragma unroll
    for (int i = 0; i < 13; ++i) {
        int yy = y - 6 + i;
        if (yy >= 0 && yy < HH) {
            float4 v = interm[((size_t)b * HH + yy) * WW + x];
            g0 += flt.dg[i] * v.x;   // fy channel: dg over y of (g over x)
            g1 += flt.g[i]  * v.y;   // fx channel: g over y of (dg over x)
            w0 += flt.dg[i] * v.z;
            w1 += flt.g[i]  * v.w;
        }
    }
    gimg4[(size_t)row * WW + x] =
        make_float4(10.f * g0, 10.f * g1, 10.f * w0, 10.f * w1);
}

__device__ __forceinline__ void bilin4(const float4* __restrict__ img,
                                       float py, float px, float4& out) {
    float yc = fminf(fmaxf(py, 0.f), 254.999f);
    float xc = fminf(fmaxf(px, 0.f), 254.999f);
    int y0 = (int)yc;
    int x0 = (int)xc;
    float ty = yc - (float)y0;
    float tx = xc - (float)x0;
    const float4* p00 = img + (size_t)y0 * WW + x0;
    float4 v00 = p00[0];
    float4 v01 = p00[1];
    float4 v10 = p00[WW];
    float4 v11 = p00[WW + 1];
    float w00 = (1.f - ty) * (1.f - tx), w01 = (1.f - ty) * tx;
    float w10 = ty * (1.f - tx),         w11 = ty * tx;
    out.x = v00.x * w00 + v01.x * w01 + v10.x * w10 + v11.x * w11;
    out.y = v00.y * w00 + v01.y * w01 + v10.y * w10 + v11.y * w11;
    out.z = v00.z * w00 + v01.z * w01 + v10.z * w10 + v11.z * w11;
    out.w = v00.w * w00 + v01.w * w01 + v10.w * w10 + v11.w * w11;
}

// One block per batch; thread i = node i. 50 sequential steps.
__global__ void snake_kernel(const float4* __restrict__ gimg4,
                             const float* __restrict__ node_pos,
                             const float* __restrict__ widths,
                             float4* __restrict__ nodes_out) {
    int b = blockIdx.x;
    int i = threadIdx.x;
    __shared__ float py[NN], px[NN], wd[NN], t2y[NN], t2x[NN];
    py[i] = node_pos[((size_t)b * NN + i) * 2 + 0];
    px[i] = node_pos[((size_t)b * NN + i) * 2 + 1];
    wd[i] = widths[(size_t)b * NN + i];
    const float4* img = gimg4 + (size_t)b * HH * WW;
    int im = (i > 0) ? i - 1 : 0;
    int ip = (i < NN - 1) ? i + 1 : NN - 1;
    __syncthreads();
    for (int s = 0; s < NSTEPS; ++s) {
        float d2y = py[im] - 2.f * py[i] + py[ip];
        float d2x = px[im] - 2.f * px[i] + px[ip];
        t2y[i] = d2y;
        t2x[i] = d2x;
        float4 f;
        bilin4(img, py[i], px[i], f);       // f.x=ch0(y-force), f.y=ch1(x-force)
        __syncthreads();                     // t2 visible; all p reads done
        float d4y = t2y[im] - 2.f * t2y[i] + t2y[ip];
        float d4x = t2x[im] - 2.f * t2x[i] + t2x[ip];
        float npy = py[i] + STEPSZ * (ALPHA * d2y - BETA * d4y + f.x);
        float npx = px[i] + STEPSZ * (ALPHA * d2x - BETA * d4x + f.y);
        npy = fminf(fmaxf(npy, 0.f), (float)(HH - 1));
        npx = fminf(fmaxf(npx, 0.f), (float)(WW - 1));
        float4 fw4;
        bilin4(img, npy, npx, fw4);          // gimgW channels in .z/.w
        float fw = fw4.z + fw4.w;
        float d2w = wd[im] - 2.f * wd[i] + wd[ip];
        float nw = wd[i] + STEPSZ * (ALPHA * d2w + fw);
        nw = fminf(fmaxf(nw, 0.f), DMAX);
        __syncthreads();                     // all t2 / wd reads done
        py[i] = npy;
        px[i] = npx;
        wd[i] = nw;
        __syncthreads();                     // new state visible
    }
    nodes_out[(size_t)b * NN + i] = make_float4(py[i], px[i], wd[i], 0.f);
}

// One block = one image row. min over 256 nodes (LDS), fused squared-error
// reduction into a single float accumulator.
__global__ void render_loss_kernel(const float* __restrict__ pd,
                                   const float4* __restrict__ nodes,
                                   float* __restrict__ acc) {
    int row = blockIdx.x;                    // b*H + y
    int b = row / HH;
    int y = row % HH;
    int x = threadIdx.x;
    __shared__ float4 nd[NN];
    nd[x] = nodes[(size_t)b * NN + x];
    __syncthreads();
    float fy = (float)y, fx = (float)x;
    float m = 1e30f;
#pragma unroll 4
    for (int n = 0; n < NN; ++n) {
        float4 p = nd[n];
        float dy = fy - p.x;
        float dx = fx - p.y;
        float d = sqrtf(dy * dy + dx * dx) - p.z;
        m = fminf(m, d);
    }
    float dm = fminf(fmaxf(m, 0.f), DMAX);
    float diff = pd[(size_t)row * WW + x] - dm;
    float v = diff * diff;
    // wave64 reduce then cross-wave
    for (int off = 32; off > 0; off >>= 1) v += __shfl_down(v, off, 64);
    __shared__ float wsum[4];
    if ((x & 63) == 0) wsum[x >> 6] = v;
    __syncthreads();
    if (x == 0) atomicAdd(acc, wsum[0] + wsum[1] + wsum[2] + wsum[3]);
}

__global__ void finalize_kernel(const float* __restrict__ acc,
                                float* __restrict__ out) {
    out[0] = acc[0] * (1.f / (float)(NB * HH * WW));
}

extern "C" void kernel_launch(void* const* d_in, const int* in_sizes, int n_in,
                              void* d_out, int out_size, void* d_ws, size_t ws_size,
                              hipStream_t stream) {
    const float* pd       = (const float*)d_in[0];   // (B,1,H,W)
    const float* node_pos = (const float*)d_in[1];   // (B,N,2)
    const float* widths   = (const float*)d_in[2];   // (B,N)
    float* out = (float*)d_out;

    char* ws = (char*)d_ws;
    size_t img_bytes = (size_t)NB * HH * WW * sizeof(float4);  // 4 MB
    float4* interm = (float4*)ws;
    float4* gimg4  = (float4*)(ws + img_bytes);
    float4* nodes  = (float4*)(ws + 2 * img_bytes);
    float*  acc    = (float*)(ws + 2 * img_bytes + (size_t)NB * NN * sizeof(float4));

    // Filter taps (stdev=2, radius 6), computed identically to the reference.
    Flt flt;
    {
        float g[13];
        float s = 0.f;
        for (int i = 0; i < 13; ++i) {
            float xx = (float)(i - 6);
            g[i] = expf(-xx * xx / 8.f);
            s += g[i];
        }
        for (int i = 0; i < 13; ++i) {
            flt.g[i]  = g[i] / s;
            flt.dg[i] = -(float)(i - 6) / 4.f * flt.g[i];
        }
    }

    hipMemsetAsync(acc, 0, sizeof(float), stream);
    conv_h_kernel<<<NB * HH, WW, 0, stream>>>(pd, interm, flt);
    conv_v_kernel<<<NB * HH, WW, 0, stream>>>(interm, gimg4, flt);
    snake_kernel<<<NB, NN, 0, stream>>>(gimg4, node_pos, widths, nodes);
    render_loss_kernel<<<NB * HH, WW, 0, stream>>>(pd, nodes, acc);
    finalize_kernel<<<1, 1, 0, stream>>>(acc, out);
}